// Round 8
// baseline (9593.992 us; speedup 1.0000x reference)
//
#include <hip/hip_runtime.h>
#include <cstdint>

typedef _Float16 f16;
typedef f16      f16x8 __attribute__((ext_vector_type(8)));
typedef float    f32x4 __attribute__((ext_vector_type(4)));
typedef uint32_t u32;
typedef u32      u32x4 __attribute__((ext_vector_type(4)));

#define NB    32
#define TT    1024
#define DD    512
#define HH    512
#define NBHH  (NB*HH)   // u32 granules per parity buffer (16384 = 64KB)
#define NWG   64

__device__ __forceinline__ float fsig(float x) {
    return __builtin_amdgcn_rcpf(1.0f + __expf(-x));
}
__device__ __forceinline__ float ftanh(float x) {
    return 1.0f - 2.0f * __builtin_amdgcn_rcpf(__expf(2.0f * x) + 1.0f);
}
__device__ __forceinline__ u32 pkmin(u32 a, u32 b) {
    u32 d; asm("v_pk_min_u16 %0, %1, %2" : "=v"(d) : "v"(a), "v"(b)); return d;
}

// ---- setup kernels -------------------------------------------------------

__global__ void k_cast_x(const float* __restrict__ x, f16* __restrict__ x16) {
    int i = (blockIdx.x * 256 + threadIdx.x) * 8;
    float4 a = *(const float4*)(x + i);
    float4 c = *(const float4*)(x + i + 4);
    f16x8 v;
    v[0] = (f16)a.x; v[1] = (f16)a.y; v[2] = (f16)a.z; v[3] = (f16)a.w;
    v[4] = (f16)c.x; v[5] = (f16)c.y; v[6] = (f16)c.z; v[7] = (f16)c.w;
    *(f16x8*)(x16 + i) = v;
}

// W (512 x 2048 row-major) -> Wp[colp][k] f16; colp = wg*32 + j*4 + gate,
// col2048 = gate*512 + wg*8 + j.
__global__ void k_perm_w(const float* __restrict__ W, f16* __restrict__ Wp) {
    int tid = blockIdx.x * 256 + threadIdx.x;   // 2048*512
    int colp = tid >> 9, k = tid & 511;
    int wg = colp >> 5, c = colp & 31;
    int gate = c & 3, j = c >> 2;
    int col = gate * 512 + wg * 8 + j;
    Wp[tid] = (f16)W[k * 2048 + col];
}

// h0 -> tagged dwords (tag 0) covering ALL of parity-1 (erases stale replay data).
__global__ void k_h0(const float* __restrict__ h0, u32* __restrict__ hb32) {
    int i = blockIdx.x * 256 + threadIdx.x;     // 16384
    f16 v = (f16)h0[i];
    hb32[NBHH + i] = (u32)__builtin_bit_cast(unsigned short, v);
}

// ---- bulk tagged-load helper (256B contiguous per thread) ----------------

#define TLD(I, OFF) asm volatile("global_load_dwordx4 %0, %1, off" OFF " sc0 sc1" \
                                 : "=v"(raw[I]) : "v"(gp))
__device__ __forceinline__ void issue_bulk(u32x4* raw, const u32* gp) {
    TLD(0,  "");             TLD(1,  " offset:16");
    TLD(2,  " offset:32");   TLD(3,  " offset:48");
    TLD(4,  " offset:64");   TLD(5,  " offset:80");
    TLD(6,  " offset:96");   TLD(7,  " offset:112");
    TLD(8,  " offset:128");  TLD(9,  " offset:144");
    TLD(10, " offset:160");  TLD(11, " offset:176");
    TLD(12, " offset:192");  TLD(13, " offset:208");
    TLD(14, " offset:224");  TLD(15, " offset:240");
}
#undef TLD

__device__ __forceinline__ u32 tagmin16(const u32x4* raw) {
    u32 m[16];
    #pragma unroll
    for (int i = 0; i < 16; ++i)
        m[i] = pkmin(pkmin(raw[i][0], raw[i][1]), pkmin(raw[i][2], raw[i][3]));
    #pragma unroll
    for (int s = 8; s >= 1; s >>= 1)
        #pragma unroll
        for (int i = 0; i < s; ++i) m[i] = pkmin(m[i], m[i + s]);
    return m[0] >> 16;       // min over the 64 high-half tags
}

// ---- persistent LSTM kernel ---------------------------------------------
// 64 WGs x 256 threads. ZERO flag hops: h stored as (tag16|f16) dwords,
// publish = the data store, detect = the bulk data load + register tag min.
// Dual parity; tag for h_t is t+1; consumer at step t wants tag == t.
// Safety: all-of-h_t visible  =>  every WG completed its h_{t-1} loads
// (publish is program-ordered after the accepted load), so parity reuse
// never overwrites unread data. Per-launch re-init erases stale tags.

__global__ void __launch_bounds__(256, 1) k_lstm(
    const f16* __restrict__ x16, const f16* __restrict__ Wxp,
    const f16* __restrict__ Whp, const float* __restrict__ bb,
    u32* hbuf32, float* __restrict__ out)
{
    __shared__ __align__(16) unsigned char lds_h[2][32768]; // unpacked h halves
    __shared__ float lds_out[8192];                         // 32 steps x 256 outs

    const int wg  = blockIdx.x;
    const int tid = threadIdx.x;
    const int w   = tid >> 6;
    const int l   = tid & 63;
    const int mt  = w >> 1, nt = w & 1;
    const int lq  = l >> 4, lc = l & 15;

    const int colp = wg * 32 + nt * 16 + lc;   // permuted gate column
    const int gate = lc & 3, j_in = lc >> 2;
    const int hcol = wg * 8 + nt * 4 + j_in;
    const int hc8  = nt * 4 + j_in;
    const float bv = bb[gate * 512 + hcol];

    const int arow   = mt * 16 + lc;           // A-fragment row (batch index)
    const int rm     = l & 3;                  // == gate
    const int n_mine = mt * 16 + lq * 4 + rm;  // row this lane publishes

    // bulk-load geometry: thread covers row brow, cols [bpart*64, bpart*64+64)
    const int brow  = tid >> 3;
    const int bpart = tid & 7;

    // Wh and Wx fragments resident in VGPRs for the whole sequence.
    f16x8 Bh[16], Bx[16];
    {
        const f16* ph = Whp + (size_t)colp * 512 + lq * 8;
        const f16* px = Wxp + (size_t)colp * 512 + lq * 8;
        #pragma unroll
        for (int ks = 0; ks < 16; ++ks) {
            Bh[ks] = *(const f16x8*)(ph + ks * 32);
            Bx[ks] = *(const f16x8*)(px + ks * 32);
        }
    }

    const f16* xptr = x16 + (size_t)arow * (TT * DD) + lq * 8;
    u32* pubp = hbuf32 + n_mine * 512 + hcol;        // parity-0 publish slot

    float c_reg[4] = {0.f, 0.f, 0.f, 0.f};

    for (int t = 0; t < TT; ++t) {
        // ---- 1) issue bulk tagged load of h_{t-1} (parity (t&1)^1) early
        const u32* gp = hbuf32 + (((t & 1) ^ 1) ? NBHH : 0) + brow * 512 + bpart * 64;
        u32x4 raw[16];
        issue_bulk(raw, gp);

        // ---- 2) x_t @ Wx + b  (hides the h-load round trip)
        f32x4 acc = {bv, bv, bv, bv};
        {
            const f16* xp = xptr + (size_t)t * DD;
            #pragma unroll
            for (int ks = 0; ks < 16; ++ks) {
                f16x8 ax = *(const f16x8*)(xp + ks * 32);
                acc = __builtin_amdgcn_mfma_f32_16x16x32_f16(ax, Bx[ks], acc, 0, 0, 0);
            }
        }

        // ---- 3) tag check; targeted per-thread retry with backoff
        asm volatile("s_waitcnt vmcnt(0)" ::: "memory");
        __builtin_amdgcn_sched_barrier(0);
        {
            const u32 want = (u32)t;
            u32 tmin = tagmin16(raw);
            int guard = 0;
            while (tmin != want && guard < (1 << 20)) {
                __builtin_amdgcn_s_sleep(1);
                issue_bulk(raw, gp);
                asm volatile("s_waitcnt vmcnt(0)" ::: "memory");
                tmin = tagmin16(raw);
                ++guard;
            }
        }
        __builtin_amdgcn_sched_barrier(0);

        // ---- 4) unpack (strip tags) into LDS half t&1, swizzled
        {
            unsigned char* lbase = &lds_h[t & 1][brow * 1024];
            const int swz = (brow & 7) << 4;
            #pragma unroll
            for (int c16 = 0; c16 < 8; ++c16) {
                u32x4 a = raw[2 * c16], b2 = raw[2 * c16 + 1];
                u32x4 wv;
                wv[0] = __builtin_amdgcn_perm(a[1],  a[0],  0x05040100u);
                wv[1] = __builtin_amdgcn_perm(a[3],  a[2],  0x05040100u);
                wv[2] = __builtin_amdgcn_perm(b2[1], b2[0], 0x05040100u);
                wv[3] = __builtin_amdgcn_perm(b2[3], b2[2], 0x05040100u);
                *(u32x4*)(lbase + ((bpart * 128 + c16 * 16) ^ swz)) = wv;
            }
        }
        __syncthreads();

        // ---- 5) h_{t-1} @ Wh from LDS
        {
            const unsigned char* abase = &lds_h[t & 1][arow * 1024];
            const int swzA = (arow & 7) << 4;
            #pragma unroll
            for (int ks = 0; ks < 16; ++ks) {
                u32x4 a = *(const u32x4*)(abase + ((lq * 16 + ks * 64) ^ swzA));
                acc = __builtin_amdgcn_mfma_f32_16x16x32_f16(
                          __builtin_bit_cast(f16x8, a), Bh[ks], acc, 0, 0, 0);
            }
        }

        // ---- 6) gates (quad-redundant c state, intra-quad shuffles)
        float hv = 0.f;
        #pragma unroll
        for (int r = 0; r < 4; ++r) {
            float av = acc[r];
            int base = l & ~3;
            float ai = __shfl(av, base | 0, 64);
            float af = __shfl(av, base | 1, 64);
            float ao = __shfl(av, base | 2, 64);
            float ag = __shfl(av, base | 3, 64);
            float ig = fsig(ai), fg = fsig(af), og = fsig(ao), gg = ftanh(ag);
            float cn = fg * c_reg[r] + ig * gg;
            c_reg[r] = cn;
            float h = og * ftanh(cn);
            if (r == rm) hv = h;
        }

        // ---- 7) publish tagged h_t (tag t+1, parity t&1) — no drain, no flag
        {
            f16 h16 = (f16)hv;
            u32 pub = ((u32)(t + 1) << 16) | (u32)__builtin_bit_cast(unsigned short, h16);
            u32* pdst = pubp + ((t & 1) ? NBHH : 0);
            asm volatile("global_store_dword %0, %1, off sc0 sc1"
                         :: "v"(pdst), "v"(pub) : "memory");
            lds_out[(t & 31) * 256 + n_mine * 8 + hc8] = hv;
        }

        // ---- 8) flush 32 steps of out (plain cached float4, off hot path)
        if ((t & 31) == 31) {
            __syncthreads();
            #pragma unroll
            for (int k2 = 0; k2 < 8; ++k2) {
                int tau = tid + 256 * k2;         // (s*32 + n)*2 + hc4
                int s   = tau >> 6;
                int n2  = (tau >> 1) & 31;
                int hc4 = tau & 1;
                float4 v = *(const float4*)&lds_out[s * 256 + n2 * 8 + hc4 * 4];
                float* op = out + (size_t)n2 * (TT * HH)
                                + (size_t)(t - 31 + s) * HH + wg * 8 + hc4 * 4;
                *(float4*)op = v;
            }
        }
    }
}

// ---- launch --------------------------------------------------------------

extern "C" void kernel_launch(void* const* d_in, const int* in_sizes, int n_in,
                              void* d_out, int out_size, void* d_ws, size_t ws_size,
                              hipStream_t stream)
{
    (void)in_sizes; (void)n_in; (void)out_size; (void)ws_size;
    const float* x  = (const float*)d_in[0];
    const float* h0 = (const float*)d_in[1];
    const float* Wx = (const float*)d_in[2];
    const float* Wh = (const float*)d_in[3];
    const float* b  = (const float*)d_in[4];
    float* out = (float*)d_out;

    char* ws = (char*)d_ws;
    f16* x16    = (f16*)ws;                        // 32 MiB
    f16* Wxp    = (f16*)(ws + (32 << 20));         // 2 MiB
    f16* Whp    = (f16*)(ws + (34 << 20));         // 2 MiB
    u32* hbuf32 = (u32*)(ws + (36 << 20));         // 2 x 64 KiB tagged h

    // parity 0 -> tag 0 (stale replay tags erased; expected parity-0 tags are odd)
    hipMemsetAsync(hbuf32, 0, NBHH * sizeof(u32), stream);
    k_cast_x<<<8192, 256, 0, stream>>>(x, x16);
    k_perm_w<<<4096, 256, 0, stream>>>(Wx, Wxp);
    k_perm_w<<<4096, 256, 0, stream>>>(Wh, Whp);
    k_h0<<<64, 256, 0, stream>>>(h0, hbuf32);      // parity 1 fully rewritten, tag 0
    k_lstm<<<NWG, 256, 0, stream>>>(x16, Wxp, Whp, b, hbuf32, out);
}

// Round 10
// 4588.145 us; speedup vs baseline: 2.0910x; 2.0910x over previous
//
#include <hip/hip_runtime.h>
#include <cstdint>

typedef _Float16 f16;
typedef f16      f16x8 __attribute__((ext_vector_type(8)));
typedef float    f32x4 __attribute__((ext_vector_type(4)));
typedef uint32_t u32;
typedef u32      u32x4 __attribute__((ext_vector_type(4)));

#define NB    32
#define TT    1024
#define DD    512
#define HH    512
#define NBHH  (NB*HH)
#define NWG   64

__device__ __forceinline__ float fsig(float x) {
    return __builtin_amdgcn_rcpf(1.0f + __expf(-x));
}
__device__ __forceinline__ float ftanh(float x) {
    return 1.0f - 2.0f * __builtin_amdgcn_rcpf(__expf(2.0f * x) + 1.0f);
}

// ---- setup kernels -------------------------------------------------------

__global__ void k_cast_x(const float* __restrict__ x, f16* __restrict__ x16) {
    int i = (blockIdx.x * 256 + threadIdx.x) * 8;
    float4 a = *(const float4*)(x + i);
    float4 c = *(const float4*)(x + i + 4);
    f16x8 v;
    v[0] = (f16)a.x; v[1] = (f16)a.y; v[2] = (f16)a.z; v[3] = (f16)a.w;
    v[4] = (f16)c.x; v[5] = (f16)c.y; v[6] = (f16)c.z; v[7] = (f16)c.w;
    *(f16x8*)(x16 + i) = v;
}

// W (512 x 2048 row-major) -> Wp[colp][k] f16; colp = wg*32 + j*4 + gate,
// col2048 = gate*512 + wg*8 + j.
__global__ void k_perm_w(const float* __restrict__ W, f16* __restrict__ Wp) {
    int tid = blockIdx.x * 256 + threadIdx.x;   // 2048*512
    int colp = tid >> 9, k = tid & 511;
    int wg = colp >> 5, c = colp & 31;
    int gate = c & 3, j = c >> 2;
    int col = gate * 512 + wg * 8 + j;
    Wp[tid] = (f16)W[k * 2048 + col];
}

// h0 -> f16 into buffer 1 (consumed at t=0); dispatch-boundary coherence.
__global__ void k_h0(const float* __restrict__ h0, f16* __restrict__ hb) {
    int i = blockIdx.x * 256 + threadIdx.x;     // 32*512
    hb[i] = (f16)h0[i];
}

// ---- persistent LSTM kernel ---------------------------------------------
// 64 WGs x 256 threads. Monotone per-WG flags (64), dual-parity h buffers,
// device scope (sc0 sc1) for all cross-WG traffic. R5 structure with ONE
// change: only wave0 lanes 0-15 poll (16 dwordx4 cover all 64 flags),
// with s_sleep backoff -> device-wide poll traffic /16 (MALL congestion fix).

__global__ void __launch_bounds__(256, 1) k_lstm(
    const f16* __restrict__ x16, const f16* __restrict__ Wxp,
    const f16* __restrict__ Whp, const float* __restrict__ bb,
    f16* hbuf, u32* flags, float* __restrict__ out)
{
    __shared__ unsigned char lds_h[32768];   // staged h_{t-1} (swizzled)
    __shared__ u32           lds_pub[256];   // this WG's h_t slice (32n x 8c)
    __shared__ float         lds_out[8192];  // 32 steps x 256 out values

    const int wg  = blockIdx.x;
    const int tid = threadIdx.x;
    const int w   = tid >> 6;
    const int l   = tid & 63;
    const int mt  = w >> 1, nt = w & 1;
    const int lq  = l >> 4, lc = l & 15;

    const int colp = wg * 32 + nt * 16 + lc;   // permuted gate column
    const int gate = lc & 3, j_in = lc >> 2;
    const int hcol = wg * 8 + nt * 4 + j_in;
    const int hc8  = nt * 4 + j_in;            // 0..7 within WG slice
    const float bv = bb[gate * 512 + hcol];

    const int arow   = mt * 16 + lc;           // A-fragment row (batch index)
    const int rm     = l & 3;                  // == gate
    const int n_mine = mt * 16 + lq * 4 + rm;  // row this lane produces

    // Wh and Wx fragments resident in VGPRs for the whole sequence.
    f16x8 Bh[16], Bx[16];
    {
        const f16* ph = Whp + (size_t)colp * 512 + lq * 8;
        const f16* px = Wxp + (size_t)colp * 512 + lq * 8;
        #pragma unroll
        for (int ks = 0; ks < 16; ++ks) {
            Bh[ks] = *(const f16x8*)(ph + ks * 32);
            Bx[ks] = *(const f16x8*)(px + ks * 32);
        }
    }

    const f16* xptr = x16 + (size_t)arow * (TT * DD) + lq * 8;

    float c_reg[4] = {0.f, 0.f, 0.f, 0.f};

    for (int t = 0; t < TT; ++t) {
        // ---- x_t @ Wx + b : independent of h, overlaps others' tails
        f32x4 acc = {bv, bv, bv, bv};
        {
            const f16* xp = xptr + (size_t)t * DD;
            #pragma unroll
            for (int ks = 0; ks < 16; ++ks) {
                f16x8 ax = *(const f16x8*)(xp + ks * 32);
                acc = __builtin_amdgcn_mfma_f32_16x16x32_f16(ax, Bx[ks], acc, 0, 0, 0);
            }
        }
        // ---- poll: wave0 lanes 0-15 only (16 x dwordx4 = all 64 flags);
        //      s_sleep(1) backoff; other waves wait at the barrier.
        if (t) {
            if (w == 0 && l < 16) {
                const u32* fl = flags + l * 4;
                int guard = 0;
                for (;;) {
                    u32x4 f;
                    asm volatile("global_load_dwordx4 %0, %1, off sc0 sc1"
                                 : "=v"(f) : "v"(fl));
                    asm volatile("s_waitcnt vmcnt(0)" ::: "memory");
                    u32 m0 = f[0] < f[1] ? f[0] : f[1];
                    u32 m1 = f[2] < f[3] ? f[2] : f[3];
                    u32 m  = m0 < m1 ? m0 : m1;
                    if (__all(m >= (u32)t) || ++guard > (1 << 20)) break;
                    __builtin_amdgcn_s_sleep(1);
                }
            }
            __syncthreads();
        }
        __builtin_amdgcn_sched_barrier(0);
        // ---- cooperative stage: full 32KB h_{t-1} -> LDS, wave-contiguous
        {
            const char* gp = (const char*)(hbuf + ((t & 1) ? 0 : NBHH)) + tid * 16;
            u32x4 hv4[8];
            #pragma unroll
            for (int r = 0; r < 8; ++r) {
                const char* p = gp + r * 4096;
                asm volatile("global_load_dwordx4 %0, %1, off sc0 sc1"
                             : "=v"(hv4[r]) : "v"(p));
            }
            asm volatile("s_waitcnt vmcnt(0)" ::: "memory");
            __builtin_amdgcn_sched_barrier(0);
            const int inrow = (tid & 63) * 16;
            #pragma unroll
            for (int r = 0; r < 8; ++r) {
                int row = (tid >> 6) + 4 * r;
                int off = row * 1024 + (inrow ^ ((row & 7) << 4));
                *(u32x4*)&lds_h[off] = hv4[r];
            }
        }
        __syncthreads();
        // ---- h_{t-1} @ Wh from LDS (2-way banked via XOR swizzle)
        {
            const int swz   = (arow & 7) << 4;
            const int baseA = arow * 1024;
            #pragma unroll
            for (int ks = 0; ks < 16; ++ks) {
                int inrowA = lq * 16 + ks * 64;
                u32x4 a = *(const u32x4*)&lds_h[baseA + (inrowA ^ swz)];
                acc = __builtin_amdgcn_mfma_f32_16x16x32_f16(
                          __builtin_bit_cast(f16x8, a), Bh[ks], acc, 0, 0, 0);
            }
        }
        // ---- gates (quad-redundant c state, intra-quad shuffles)
        float hv = 0.f;
        #pragma unroll
        for (int r = 0; r < 4; ++r) {
            float av = acc[r];
            int base = l & ~3;
            float ai = __shfl(av, base | 0, 64);
            float af = __shfl(av, base | 1, 64);
            float ao = __shfl(av, base | 2, 64);
            float ag = __shfl(av, base | 3, 64);
            float ig = fsig(ai), fg = fsig(af), og = fsig(ao), gg = ftanh(ag);
            float cn = fg * c_reg[r] + ig * gg;
            c_reg[r] = cn;
            float h = og * ftanh(cn);
            if (r == rm) hv = h;
        }
        // ---- stage h_t slice + out value in LDS
        {
            f16 h16 = (f16)hv;
            lds_pub[n_mine * 8 + hc8] = (u32)__builtin_bit_cast(unsigned short, h16);
            lds_out[(t & 31) * 256 + n_mine * 8 + hc8] = hv;
        }
        __syncthreads();
        // ---- wave0: publish WG slice as 32 x 16B write-through, drain, flag
        if (w == 0) {
            if (tid < 32) {
                const u32* pp = lds_pub + tid * 8;
                u32 p0 = (pp[0] & 0xffffu) | (pp[1] << 16);
                u32 p1 = (pp[2] & 0xffffu) | (pp[3] << 16);
                u32 p2 = (pp[4] & 0xffffu) | (pp[5] << 16);
                u32 p3 = (pp[6] & 0xffffu) | (pp[7] << 16);
                u32x4 pv = {p0, p1, p2, p3};
                f16* hdst = hbuf + ((t & 1) ? NBHH : 0) + tid * HH + wg * 8;
                asm volatile("global_store_dwordx4 %0, %1, off sc0 sc1"
                             :: "v"(hdst), "v"(pv) : "memory");
            }
            asm volatile("s_waitcnt vmcnt(0)" ::: "memory");
            if (tid == 0) {
                u32 fv = (u32)(t + 1);
                u32* mf = flags + wg;
                asm volatile("global_store_dword %0, %1, off sc0 sc1"
                             :: "v"(mf), "v"(fv) : "memory");
            }
        }
        // ---- flush 32 steps of out (plain cached float4, off hot path)
        if ((t & 31) == 31) {
            #pragma unroll
            for (int r2 = 0; r2 < 8; ++r2) {
                int tau = tid + 256 * r2;         // (s*32 + n)*2 + hc4
                int s   = tau >> 6;
                int n2  = (tau >> 1) & 31;
                int hc4 = tau & 1;
                float4 v = *(const float4*)&lds_out[s * 256 + n2 * 8 + hc4 * 4];
                float* op = out + (size_t)n2 * (TT * HH)
                                + (size_t)(t - 31 + s) * HH + wg * 8 + hc4 * 4;
                *(float4*)op = v;
            }
        }
    }
}

// ---- launch --------------------------------------------------------------

extern "C" void kernel_launch(void* const* d_in, const int* in_sizes, int n_in,
                              void* d_out, int out_size, void* d_ws, size_t ws_size,
                              hipStream_t stream)
{
    (void)in_sizes; (void)n_in; (void)out_size; (void)ws_size;
    const float* x  = (const float*)d_in[0];
    const float* h0 = (const float*)d_in[1];
    const float* Wx = (const float*)d_in[2];
    const float* Wh = (const float*)d_in[3];
    const float* b  = (const float*)d_in[4];
    float* out = (float*)d_out;

    char* ws = (char*)d_ws;
    u32* flags = (u32*)ws;                               // 4 KiB reserved
    f16* x16   = (f16*)(ws + (4 << 10));                 // 32 MiB
    f16* Wxp   = (f16*)(ws + (4 << 10) + (32 << 20));    // 2 MiB
    f16* Whp   = (f16*)(ws + (4 << 10) + (34 << 20));    // 2 MiB
    f16* hbuf  = (f16*)(ws + (4 << 10) + (36 << 20));    // 2 x 64 KiB

    hipMemsetAsync(flags, 0, 4096, stream);
    k_cast_x<<<8192, 256, 0, stream>>>(x, x16);
    k_perm_w<<<4096, 256, 0, stream>>>(Wx, Wxp);
    k_perm_w<<<4096, 256, 0, stream>>>(Wh, Whp);
    k_h0<<<64, 256, 0, stream>>>(h0, hbuf + NBHH);       // buffer 1 = h_{-1}
    k_lstm<<<NWG, 256, 0, stream>>>(x16, Wxp, Whp, b, hbuf, flags, out);
}